// Round 13
// baseline (134.608 us; speedup 1.0000x reference)
//
#include <hip/hip_runtime.h>
#include <hip/hip_bf16.h>
#include <stdint.h>

// DenseConv2d: input (32,128,56,56) f32, weight (256,128,3,3) f32, bias (256) f32
// stride 1, pad 1 -> out (32,256,56,56) f32.
// Round 13: ZERO-LDS, ZERO-BARRIER direct-to-register implicit GEMM.
// Both operands are pre-laid-out in MFMA fragment order in ws (w3 chunks for A,
// padded NHWC for B), so each fragment is ONE contiguous 1KB wave read via
// global_load_dwordx4. Waves are fully independent [16 loads -> 32 MFMA]
// streams; compiler inserts counted vmcnt; TLP = 3 waves/SIMD hides latency.
// L1 serves A (shared per CU) and B (2x reuse). 128x128 block, 64x64/wave.

typedef __attribute__((ext_vector_type(8))) short bf16x8;
typedef __attribute__((ext_vector_type(8))) unsigned short ushort8;
typedef __attribute__((ext_vector_type(4))) float f32x4;

#define HW       56
#define SPATIAL  3136
#define C_IN     128
#define K_OUT    256
#define GEMM_K   1152
#define GEMM_N   100352      // 32*3136

#define PHW      58
#define PIMG     3364        // 58*58
#define PADTOT_AL 107656     // 32*3364 + 8 slack positions

#define NTILE    18          // K-tiles of 64 (tap = t>>1, ch-half = t&1)

__device__ __forceinline__ unsigned short f2bf(float f) {
    union { float f; unsigned int u; } v; v.f = f;
    unsigned int u = v.u + 0x7FFFu + ((v.u >> 16) & 1u);   // RTNE
    return (unsigned short)(u >> 16);
}

// weight [256][128][3][3] f32 -> w3: chunk (rc,tap,cc) = 512 halves; slot
// s = l*8+j holds W[row rc*16 + (l&15)][ch cc*32 + (l>>4)*8 + j][tap].
// One chunk == one wave's A-fragment for MFMA 16x16x32 (verified r9-r12).
__global__ void wtrans_kernel(const float* __restrict__ w, unsigned short* __restrict__ w3) {
    int idx = blockIdx.x * 256 + threadIdx.x;    // 294912
    int rc   = idx / 18432;
    int rem  = idx % 18432;
    int tap  = rem / 2048;
    int rem2 = rem % 2048;
    int cc   = rem2 / 512;
    int s    = rem2 % 512;
    int l    = s >> 3, j = s & 7;
    int ko   = rc * 16 + (l & 15);
    int c    = cc * 32 + ((l >> 4) << 3) + j;
    w3[idx] = f2bf(w[(ko * C_IN + c) * 9 + tap]);
}

// zero only the border ring of pad[4][32][58*58][32] (1.9 MB)
__global__ __launch_bounds__(256)
void border_zero(unsigned short* __restrict__ pad) {
    int idx = blockIdx.x * 256 + threadIdx.x;    // 4*32*228 = 29184
    if (idx >= 29184) return;
    int cc  = idx / 7296;
    int r   = idx % 7296;
    int img = r / 228;
    int p   = r % 228;
    int pos;
    if (p < 58)       pos = p;
    else if (p < 116) pos = 57 * PHW + (p - 58);
    else { int i = p - 116; pos = (1 + (i >> 1)) * PHW + (i & 1) * 57; }
    unsigned short* d = pad + (size_t)cc * PADTOT_AL * 32
                      + ((size_t)img * PIMG + pos) * 32;
    const ushort8 z = (ushort8){0,0,0,0,0,0,0,0};
    *reinterpret_cast<ushort8*>(d)      = z;
    *reinterpret_cast<ushort8*>(d + 8)  = z;
    *reinterpret_cast<ushort8*>(d + 16) = z;
    *reinterpret_cast<ushort8*>(d + 24) = z;
}

// input [32][128][56][56] f32 -> pad[4cc][32img][58*58][32ch] bf16 (interior)
__global__ __launch_bounds__(256)
void intrans_kernel(const float* __restrict__ in, unsigned short* __restrict__ pad) {
    __shared__ __attribute__((aligned(16))) unsigned short l[56 * 136];
    const int bx = blockIdx.x;                   // 32*56
    const int n = bx / HW, h = bx % HW;
    const int tid = threadIdx.x;
    const float* src = in + (size_t)n * C_IN * SPATIAL + h * HW;
    #pragma unroll
    for (int i = 0; i < 28; ++i) {               // 7168 = 28*256
        int idx = i * 256 + tid;
        int c = idx / HW, w = idx % HW;
        l[w * 136 + c] = f2bf(src[(size_t)c * SPATIAL + w]);
    }
    __syncthreads();
    const int prow = n * PIMG + (h + 1) * PHW;
    #pragma unroll
    for (int j = 0; j < 4; ++j) {
        int chunk = j * 256 + tid;               // 896 = 56*16 chunks of 8 halves
        if (chunk < 896) {
            int w = chunk >> 4, c8 = chunk & 15;
            int cc = c8 >> 2, sub = c8 & 3;
            unsigned short* dst = pad + (size_t)cc * PADTOT_AL * 32
                                + (size_t)(prow + w + 1) * 32 + sub * 8;
            *reinterpret_cast<ushort8*>(dst) =
                *reinterpret_cast<const ushort8*>(&l[w * 136 + c8 * 8]);
        }
    }
}

// ---------------- main kernel: direct-to-register, no LDS, no barriers ----------------
__global__ __launch_bounds__(256, 3)
void conv_direct(const unsigned short* __restrict__ pad,   // [4][PADTOT_AL][32]
                 const unsigned short* __restrict__ w3,    // chunked weights
                 const float* __restrict__ bias,
                 float* __restrict__ out) {
    const int tid  = threadIdx.x;
    const int wave = tid >> 6;
    const int lane = tid & 63;
    const int la   = lane & 15;
    const int lkh  = lane >> 4;

    // bijective XCD swizzle: 1568 blocks = 8 * 196; m-tile pairs adjacent so
    // an XCD's concurrent blocks share B panels in its L2.
    const int bid = blockIdx.x;
    const int swz = (bid & 7) * 196 + (bid >> 3);
    const int mt  = swz & 1, nt = swz >> 1;       // nt 0..783
    const int m0  = mt * 128;
    const int g0  = nt * 128;

    const int wr = wave >> 1, wc = wave & 1;      // 2x2 waves, 64x64 tiles

    // A fragment sources: chunk rc = m0/16 + wr*4 + mi; per-lane slot lane*8
    const unsigned short* asrc[4];
    #pragma unroll
    for (int mi = 0; mi < 4; ++mi)
        asrc[mi] = w3 + (size_t)((m0 >> 4) + wr * 4 + mi) * 18432 + lane * 8;

    // B fragment sources: col = g0 + wc*64 + bc*16 + la; per-lane padded addr
    const unsigned short* bsrc[4];
    #pragma unroll
    for (int bc = 0; bc < 4; ++bc) {
        int col = g0 + wc * 64 + bc * 16 + la;
        int img = col / SPATIAL;
        int pos = col - img * SPATIAL;
        int oh  = pos / HW, ow = pos - oh * HW;
        bsrc[bc] = pad + (size_t)(img * PIMG + (oh + 1) * PHW + (ow + 1)) * 32 + lkh * 8;
    }

    f32x4 acc[4][4];
    #pragma unroll
    for (int i = 0; i < 4; ++i)
        #pragma unroll
        for (int j = 0; j < 4; ++j)
            acc[i][j] = (f32x4){0.f, 0.f, 0.f, 0.f};

    #pragma unroll
    for (int t = 0; t < NTILE; ++t) {
        const int tap = t >> 1;
        const int dr = tap / 3 - 1, dsx = tap % 3 - 1;
        bf16x8 a[4][2], b[4][2];
        #pragma unroll
        for (int ks = 0; ks < 2; ++ks) {
            const int cc = (t & 1) * 2 + ks;              // 32-ch chunk 0..3
            const ptrdiff_t aofs = (ptrdiff_t)(tap * 4 + cc) * 512;
            const ptrdiff_t bofs = (ptrdiff_t)cc * (PADTOT_AL * 32)
                                 + (dr * PHW + dsx) * 32;
            #pragma unroll
            for (int mi = 0; mi < 4; ++mi)
                a[mi][ks] = *reinterpret_cast<const bf16x8*>(asrc[mi] + aofs);
            #pragma unroll
            for (int bc = 0; bc < 4; ++bc)
                b[bc][ks] = *reinterpret_cast<const bf16x8*>(bsrc[bc] + bofs);
        }
        __builtin_amdgcn_s_setprio(1);
        #pragma unroll
        for (int ks = 0; ks < 2; ++ks)
            #pragma unroll
            for (int mi = 0; mi < 4; ++mi)
                #pragma unroll
                for (int nj = 0; nj < 4; ++nj)
                    acc[mi][nj] = __builtin_amdgcn_mfma_f32_16x16x32_bf16(
                        a[mi][ks], b[nj][ks], acc[mi][nj], 0, 0, 0);
        __builtin_amdgcn_s_setprio(0);
    }

    // ---- epilogue: D col = lane&15, row = (lane>>4)*4 + reg ----
    #pragma unroll
    for (int mi = 0; mi < 4; ++mi) {
        const int mb = m0 + wr * 64 + mi * 16 + lkh * 4;
        const f32x4 bv4 = *reinterpret_cast<const f32x4*>(&bias[mb]);
        #pragma unroll
        for (int nj = 0; nj < 4; ++nj) {
            const int gcol = g0 + wc * 64 + nj * 16;   // 16-aligned: one image
            const int n2 = gcol / SPATIAL;
            const int p2 = gcol - n2 * SPATIAL + la;
            float* op = out + ((size_t)(n2 * K_OUT + mb)) * SPATIAL + p2;
            op[0]                   = acc[mi][nj][0] + bv4[0];
            op[SPATIAL]             = acc[mi][nj][1] + bv4[1];
            op[2 * SPATIAL]         = acc[mi][nj][2] + bv4[2];
            op[3 * (size_t)SPATIAL] = acc[mi][nj][3] + bv4[3];
        }
    }
}

// ---------------- fallback (round-1 path) if ws is too small ----------------
#define LDK 40
__global__ __launch_bounds__(256)
void conv_mfma_fallback(const float* __restrict__ in,
                        const float* __restrict__ wraw,
                        const float* __restrict__ bias,
                        float* __restrict__ out) {
    __shared__ __attribute__((aligned(16))) unsigned short lA[128 * LDK];
    __shared__ __attribute__((aligned(16))) unsigned short lB[128 * LDK];
    const int tid = threadIdx.x;
    const int m0  = blockIdx.y * 128;
    const int g0  = blockIdx.x * 128;
    const int wave = tid >> 6, lane = tid & 63;
    const int wr = wave >> 1, wc = wave & 1;
    const int la = lane & 15, lkh = lane >> 4, lk = lkh * 8;

    f32x4 acc[4][4];
    #pragma unroll
    for (int i = 0; i < 4; ++i)
        #pragma unroll
        for (int j = 0; j < 4; ++j)
            acc[i][j] = (f32x4){0.f, 0.f, 0.f, 0.f};

    const int jj = tid & 127;
    const int kb = (tid >> 7) * 16;
    const int g = g0 + jj;
    const int nimg = g / SPATIAL;
    const int pos  = g % SPATIAL;
    const int oh = pos / HW, ow = pos % HW;

    for (int tap = 0; tap < 9; ++tap) {
        const int dr = tap / 3 - 1, dsx = tap % 3 - 1;
        const int ih = oh + dr, iw = ow + dsx;
        const bool valid = ((unsigned)ih < HW) && ((unsigned)iw < HW);
        const float* src = in + ((nimg * C_IN) * HW + ih) * HW + iw;
        for (int c0 = 0; c0 < C_IN; c0 += 32) {
            #pragma unroll
            for (int i = 0; i < 2; ++i) {
                const int ch = tid * 2 + i;
                const int row = ch >> 2;
                const int kp = (ch & 3) * 8;
                ushort8 v;
                #pragma unroll
                for (int e = 0; e < 8; ++e)
                    v[e] = f2bf(wraw[((m0 + row) * C_IN + c0 + kp + e) * 9 + tap]);
                *reinterpret_cast<ushort8*>(&lA[row * LDK + kp]) = v;
            }
            {
                ushort8 v0, v1;
                #pragma unroll
                for (int i = 0; i < 8; ++i)
                    v0[i] = f2bf(valid ? src[(c0 + kb + i) * SPATIAL] : 0.f);
                #pragma unroll
                for (int i = 0; i < 8; ++i)
                    v1[i] = f2bf(valid ? src[(c0 + kb + 8 + i) * SPATIAL] : 0.f);
                *reinterpret_cast<ushort8*>(&lB[jj * LDK + kb])     = v0;
                *reinterpret_cast<ushort8*>(&lB[jj * LDK + kb + 8]) = v1;
            }
            __syncthreads();
            bf16x8 af[4], bv[4];
            #pragma unroll
            for (int f = 0; f < 4; ++f) {
                af[f] = *reinterpret_cast<const bf16x8*>(&lA[(wr * 64 + f * 16 + la) * LDK + lk]);
                bv[f] = *reinterpret_cast<const bf16x8*>(&lB[(wc * 64 + f * 16 + la) * LDK + lk]);
            }
            #pragma unroll
            for (int fi = 0; fi < 4; ++fi)
                #pragma unroll
                for (int fj = 0; fj < 4; ++fj)
                    acc[fi][fj] = __builtin_amdgcn_mfma_f32_16x16x32_bf16(
                        af[fi], bv[fj], acc[fi][fj], 0, 0, 0);
            __syncthreads();
        }
    }
    const int mbase = m0 + wr * 64;
    const int cbase = g0 + wc * 64;
    #pragma unroll
    for (int fi = 0; fi < 4; ++fi) {
        float bvv[4];
        #pragma unroll
        for (int r = 0; r < 4; ++r)
            bvv[r] = bias[mbase + fi * 16 + lkh * 4 + r];
        #pragma unroll
        for (int fj = 0; fj < 4; ++fj) {
            const int gcol = cbase + fj * 16 + la;
            const int n2 = gcol / SPATIAL;
            const int p2 = gcol % SPATIAL;
            float* op = out + (size_t)(n2 * K_OUT) * SPATIAL + p2;
            #pragma unroll
            for (int r = 0; r < 4; ++r)
                op[(size_t)(mbase + fi * 16 + lkh * 4 + r) * SPATIAL] = acc[fi][fj][r] + bvv[r];
        }
    }
}

extern "C" void kernel_launch(void* const* d_in, const int* in_sizes, int n_in,
                              void* d_out, int out_size, void* d_ws, size_t ws_size,
                              hipStream_t stream) {
    const float* in   = (const float*)d_in[0];
    const float* w    = (const float*)d_in[1];
    const float* bias = (const float*)d_in[2];
    float* out = (float*)d_out;

    // ws layout (halves): pad [4*PADTOT_AL*32] | w3 [294912]
    const size_t pad_halves = 4ull * PADTOT_AL * 32ull;     // 13,779,968
    const size_t need_bytes = (pad_halves + 294912ull) * 2ull;  // ~28.15 MB

    if (ws_size >= need_bytes) {
        unsigned short* pad = (unsigned short*)d_ws;
        unsigned short* w3  = pad + pad_halves;
        border_zero<<<114, 256, 0, stream>>>(pad);
        wtrans_kernel<<<294912 / 256, 256, 0, stream>>>(w, w3);
        intrans_kernel<<<32 * HW, 256, 0, stream>>>(in, pad);
        conv_direct<<<(GEMM_N / 128) * (K_OUT / 128), 256, 0, stream>>>(pad, w3, bias, out);
    } else {
        dim3 grid(GEMM_N / 128, K_OUT / 128);
        conv_mfma_fallback<<<grid, 256, 0, stream>>>(in, w, bias, out);
    }
}

// Round 14
// 118.288 us; speedup vs baseline: 1.1380x; 1.1380x over previous
//
#include <hip/hip_runtime.h>
#include <hip/hip_bf16.h>
#include <stdint.h>

// DenseConv2d: input (32,128,56,56) f32, weight (256,128,3,3) f32, bias (256) f32
// stride 1, pad 1 -> out (32,256,56,56) f32.
// Round 14: zero-LDS zero-barrier direct-to-register (r13) + EXPLICIT 2-tile
// register pipeline: named even/odd fragment banks (128 VGPR), tile t+1's 16
// loads issued before MFMA(t), counted s_waitcnt vmcnt(16) (never 0 until the
// tail) + sched_barrier fences. Waves fully independent; no lockstep possible.

typedef __attribute__((ext_vector_type(8))) short bf16x8;
typedef __attribute__((ext_vector_type(8))) unsigned short ushort8;
typedef __attribute__((ext_vector_type(4))) float f32x4;

#define HW       56
#define SPATIAL  3136
#define C_IN     128
#define K_OUT    256
#define GEMM_K   1152
#define GEMM_N   100352      // 32*3136

#define PHW      58
#define PIMG     3364        // 58*58
#define PADTOT_AL 107656     // 32*3364 + 8 slack positions

#define NTILE    18          // K-tiles of 64 (tap = t>>1, ch-half = t&1)

__device__ __forceinline__ unsigned short f2bf(float f) {
    union { float f; unsigned int u; } v; v.f = f;
    unsigned int u = v.u + 0x7FFFu + ((v.u >> 16) & 1u);   // RTNE
    return (unsigned short)(u >> 16);
}

// fused prepass A: blocks 0..1151 -> wtrans; 1152..1265 -> border_zero
// w3 chunk (rc,tap,cc) = 512 halves; slot s = l*8+j holds
// W[row rc*16 + (l&15)][ch cc*32 + (l>>4)*8 + j][tap]  (one wave A-fragment).
__global__ __launch_bounds__(256)
void prep_kernel(const float* __restrict__ w, unsigned short* __restrict__ w3,
                 unsigned short* __restrict__ pad) {
    if (blockIdx.x < 1152) {
        int idx = blockIdx.x * 256 + threadIdx.x;    // 294912
        int rc   = idx / 18432;
        int rem  = idx % 18432;
        int tap  = rem / 2048;
        int rem2 = rem % 2048;
        int cc   = rem2 / 512;
        int s    = rem2 % 512;
        int l    = s >> 3, j = s & 7;
        int ko   = rc * 16 + (l & 15);
        int c    = cc * 32 + ((l >> 4) << 3) + j;
        w3[idx] = f2bf(w[(ko * C_IN + c) * 9 + tap]);
    } else {
        int idx = (blockIdx.x - 1152) * 256 + threadIdx.x;   // 4*32*228 = 29184
        if (idx >= 29184) return;
        int cc  = idx / 7296;
        int r   = idx % 7296;
        int img = r / 228;
        int p   = r % 228;
        int pos;
        if (p < 58)       pos = p;
        else if (p < 116) pos = 57 * PHW + (p - 58);
        else { int i = p - 116; pos = (1 + (i >> 1)) * PHW + (i & 1) * 57; }
        unsigned short* d = pad + (size_t)cc * PADTOT_AL * 32
                          + ((size_t)img * PIMG + pos) * 32;
        const ushort8 z = (ushort8){0,0,0,0,0,0,0,0};
        *reinterpret_cast<ushort8*>(d)      = z;
        *reinterpret_cast<ushort8*>(d + 8)  = z;
        *reinterpret_cast<ushort8*>(d + 16) = z;
        *reinterpret_cast<ushort8*>(d + 24) = z;
    }
}

// input [32][128][56][56] f32 -> pad[4cc][32img][58*58][32ch] bf16 (interior)
__global__ __launch_bounds__(256)
void intrans_kernel(const float* __restrict__ in, unsigned short* __restrict__ pad) {
    __shared__ __attribute__((aligned(16))) unsigned short l[56 * 136];
    const int bx = blockIdx.x;                   // 32*56
    const int n = bx / HW, h = bx % HW;
    const int tid = threadIdx.x;
    const float* src = in + (size_t)n * C_IN * SPATIAL + h * HW;
    #pragma unroll
    for (int i = 0; i < 28; ++i) {               // 7168 = 28*256
        int idx = i * 256 + tid;
        int c = idx / HW, w = idx % HW;
        l[w * 136 + c] = f2bf(src[(size_t)c * SPATIAL + w]);
    }
    __syncthreads();
    const int prow = n * PIMG + (h + 1) * PHW;
    #pragma unroll
    for (int j = 0; j < 4; ++j) {
        int chunk = j * 256 + tid;               // 896 = 56*16 chunks of 8 halves
        if (chunk < 896) {
            int w = chunk >> 4, c8 = chunk & 15;
            int cc = c8 >> 2, sub = c8 & 3;
            unsigned short* dst = pad + (size_t)cc * PADTOT_AL * 32
                                + (size_t)(prow + w + 1) * 32 + sub * 8;
            *reinterpret_cast<ushort8*>(dst) =
                *reinterpret_cast<const ushort8*>(&l[w * 136 + c8 * 8]);
        }
    }
}

// ---------------- main kernel: direct-to-register + explicit pipeline ----------------
__global__ __launch_bounds__(256, 2)
void conv_pipe2(const unsigned short* __restrict__ pad,   // [4][PADTOT_AL][32]
                const unsigned short* __restrict__ w3,    // chunked weights
                const float* __restrict__ bias,
                float* __restrict__ out) {
    const int tid  = threadIdx.x;
    const int wave = tid >> 6;
    const int lane = tid & 63;
    const int la   = lane & 15;
    const int lkh  = lane >> 4;

    // bijective XCD swizzle: 1568 blocks = 8 * 196; m-pairs adjacent for L2 B reuse
    const int bid = blockIdx.x;
    const int swz = (bid & 7) * 196 + (bid >> 3);
    const int mt  = swz & 1, nt = swz >> 1;       // nt 0..783
    const int m0  = mt * 128;
    const int g0  = nt * 128;

    const int wr = wave >> 1, wc = wave & 1;      // 2x2 waves, 64x64 tiles

    const unsigned short* asrc[4];
    #pragma unroll
    for (int mi = 0; mi < 4; ++mi)
        asrc[mi] = w3 + (size_t)((m0 >> 4) + wr * 4 + mi) * 18432 + lane * 8;

    const unsigned short* bsrc[4];
    #pragma unroll
    for (int bc = 0; bc < 4; ++bc) {
        int col = g0 + wc * 64 + bc * 16 + la;
        int img = col / SPATIAL;
        int pos = col - img * SPATIAL;
        int oh  = pos / HW, ow = pos - oh * HW;
        bsrc[bc] = pad + (size_t)(img * PIMG + (oh + 1) * PHW + (ow + 1)) * 32 + lkh * 8;
    }

    f32x4 acc[4][4];
    #pragma unroll
    for (int i = 0; i < 4; ++i)
        #pragma unroll
        for (int j = 0; j < 4; ++j)
            acc[i][j] = (f32x4){0.f, 0.f, 0.f, 0.f};

    // even/odd fragment banks (named; all indices compile-time via full unroll)
    bf16x8 aE[8], bE[8], aO[8], bO[8];

#define LOADT(tn, A_, B_) do {                                               \
    const int tap_ = (tn) >> 1;                                              \
    const int dr_ = tap_ / 3 - 1, dx_ = tap_ % 3 - 1;                        \
    _Pragma("unroll")                                                        \
    for (int ks = 0; ks < 2; ++ks) {                                         \
        const int cc_ = ((tn) & 1) * 2 + ks;                                 \
        const ptrdiff_t ao_ = (ptrdiff_t)(tap_ * 4 + cc_) * 512;             \
        const ptrdiff_t bo_ = (ptrdiff_t)cc_ * (PADTOT_AL * 32)              \
                            + (dr_ * PHW + dx_) * 32;                        \
        _Pragma("unroll")                                                    \
        for (int mi = 0; mi < 4; ++mi)                                       \
            A_[mi * 2 + ks] = *reinterpret_cast<const bf16x8*>(asrc[mi] + ao_); \
        _Pragma("unroll")                                                    \
        for (int bc = 0; bc < 4; ++bc)                                       \
            B_[bc * 2 + ks] = *reinterpret_cast<const bf16x8*>(bsrc[bc] + bo_); \
    }                                                                        \
} while (0)

#define MFMAT(A_, B_) do {                                                   \
    __builtin_amdgcn_s_setprio(1);                                           \
    _Pragma("unroll")                                                        \
    for (int ks = 0; ks < 2; ++ks)                                           \
        _Pragma("unroll")                                                    \
        for (int mi = 0; mi < 4; ++mi)                                       \
            _Pragma("unroll")                                                \
            for (int nj = 0; nj < 4; ++nj)                                   \
                acc[mi][nj] = __builtin_amdgcn_mfma_f32_16x16x32_bf16(       \
                    A_[mi * 2 + ks], B_[nj * 2 + ks], acc[mi][nj], 0, 0, 0); \
    __builtin_amdgcn_s_setprio(0);                                           \
} while (0)

    LOADT(0, aE, bE);                  // 16 loads in flight

    #pragma unroll
    for (int t = 0; t < NTILE; ++t) {
        if ((t & 1) == 0) {
            if (t + 1 < NTILE) {
                LOADT(t + 1, aO, bO);                              // +16 -> 32
                asm volatile("s_waitcnt vmcnt(16)" ::: "memory");  // tile t landed
            } else {
                asm volatile("s_waitcnt vmcnt(0)" ::: "memory");
            }
            __builtin_amdgcn_sched_barrier(0);
            MFMAT(aE, bE);
        } else {
            if (t + 1 < NTILE) {
                LOADT(t + 1, aE, bE);
                asm volatile("s_waitcnt vmcnt(16)" ::: "memory");
            } else {
                asm volatile("s_waitcnt vmcnt(0)" ::: "memory");
            }
            __builtin_amdgcn_sched_barrier(0);
            MFMAT(aO, bO);
        }
    }

    // ---- epilogue: D col = lane&15, row = (lane>>4)*4 + reg ----
    #pragma unroll
    for (int mi = 0; mi < 4; ++mi) {
        const int mb = m0 + wr * 64 + mi * 16 + lkh * 4;
        const f32x4 bv4 = *reinterpret_cast<const f32x4*>(&bias[mb]);
        #pragma unroll
        for (int nj = 0; nj < 4; ++nj) {
            const int gcol = g0 + wc * 64 + nj * 16;   // 16-aligned: one image
            const int n2 = gcol / SPATIAL;
            const int p2 = gcol - n2 * SPATIAL + la;
            float* op = out + ((size_t)(n2 * K_OUT + mb)) * SPATIAL + p2;
            op[0]                   = acc[mi][nj][0] + bv4[0];
            op[SPATIAL]             = acc[mi][nj][1] + bv4[1];
            op[2 * SPATIAL]         = acc[mi][nj][2] + bv4[2];
            op[3 * (size_t)SPATIAL] = acc[mi][nj][3] + bv4[3];
        }
    }
#undef LOADT
#undef MFMAT
}

// ---------------- fallback (round-1 path) if ws is too small ----------------
#define LDK 40
__global__ __launch_bounds__(256)
void conv_mfma_fallback(const float* __restrict__ in,
                        const float* __restrict__ wraw,
                        const float* __restrict__ bias,
                        float* __restrict__ out) {
    __shared__ __attribute__((aligned(16))) unsigned short lA[128 * LDK];
    __shared__ __attribute__((aligned(16))) unsigned short lB[128 * LDK];
    const int tid = threadIdx.x;
    const int m0  = blockIdx.y * 128;
    const int g0  = blockIdx.x * 128;
    const int wave = tid >> 6, lane = tid & 63;
    const int wr = wave >> 1, wc = wave & 1;
    const int la = lane & 15, lkh = lane >> 4, lk = lkh * 8;

    f32x4 acc[4][4];
    #pragma unroll
    for (int i = 0; i < 4; ++i)
        #pragma unroll
        for (int j = 0; j < 4; ++j)
            acc[i][j] = (f32x4){0.f, 0.f, 0.f, 0.f};

    const int jj = tid & 127;
    const int kb = (tid >> 7) * 16;
    const int g = g0 + jj;
    const int nimg = g / SPATIAL;
    const int pos  = g % SPATIAL;
    const int oh = pos / HW, ow = pos % HW;

    for (int tap = 0; tap < 9; ++tap) {
        const int dr = tap / 3 - 1, dsx = tap % 3 - 1;
        const int ih = oh + dr, iw = ow + dsx;
        const bool valid = ((unsigned)ih < HW) && ((unsigned)iw < HW);
        const float* src = in + ((nimg * C_IN) * HW + ih) * HW + iw;
        for (int c0 = 0; c0 < C_IN; c0 += 32) {
            #pragma unroll
            for (int i = 0; i < 2; ++i) {
                const int ch = tid * 2 + i;
                const int row = ch >> 2;
                const int kp = (ch & 3) * 8;
                ushort8 v;
                #pragma unroll
                for (int e = 0; e < 8; ++e)
                    v[e] = f2bf(wraw[((m0 + row) * C_IN + c0 + kp + e) * 9 + tap]);
                *reinterpret_cast<ushort8*>(&lA[row * LDK + kp]) = v;
            }
            {
                ushort8 v0, v1;
                #pragma unroll
                for (int i = 0; i < 8; ++i)
                    v0[i] = f2bf(valid ? src[(c0 + kb + i) * SPATIAL] : 0.f);
                #pragma unroll
                for (int i = 0; i < 8; ++i)
                    v1[i] = f2bf(valid ? src[(c0 + kb + 8 + i) * SPATIAL] : 0.f);
                *reinterpret_cast<ushort8*>(&lB[jj * LDK + kb])     = v0;
                *reinterpret_cast<ushort8*>(&lB[jj * LDK + kb + 8]) = v1;
            }
            __syncthreads();
            bf16x8 af[4], bv[4];
            #pragma unroll
            for (int f = 0; f < 4; ++f) {
                af[f] = *reinterpret_cast<const bf16x8*>(&lA[(wr * 64 + f * 16 + la) * LDK + lk]);
                bv[f] = *reinterpret_cast<const bf16x8*>(&lB[(wc * 64 + f * 16 + la) * LDK + lk]);
            }
            #pragma unroll
            for (int fi = 0; fi < 4; ++fi)
                #pragma unroll
                for (int fj = 0; fj < 4; ++fj)
                    acc[fi][fj] = __builtin_amdgcn_mfma_f32_16x16x32_bf16(
                        af[fi], bv[fj], acc[fi][fj], 0, 0, 0);
            __syncthreads();
        }
    }
    const int mbase = m0 + wr * 64;
    const int cbase = g0 + wc * 64;
    #pragma unroll
    for (int fi = 0; fi < 4; ++fi) {
        float bvv[4];
        #pragma unroll
        for (int r = 0; r < 4; ++r)
            bvv[r] = bias[mbase + fi * 16 + lkh * 4 + r];
        #pragma unroll
        for (int fj = 0; fj < 4; ++fj) {
            const int gcol = cbase + fj * 16 + la;
            const int n2 = gcol / SPATIAL;
            const int p2 = gcol % SPATIAL;
            float* op = out + (size_t)(n2 * K_OUT) * SPATIAL + p2;
            #pragma unroll
            for (int r = 0; r < 4; ++r)
                op[(size_t)(mbase + fi * 16 + lkh * 4 + r) * SPATIAL] = acc[fi][fj][r] + bvv[r];
        }
    }
}

extern "C" void kernel_launch(void* const* d_in, const int* in_sizes, int n_in,
                              void* d_out, int out_size, void* d_ws, size_t ws_size,
                              hipStream_t stream) {
    const float* in   = (const float*)d_in[0];
    const float* w    = (const float*)d_in[1];
    const float* bias = (const float*)d_in[2];
    float* out = (float*)d_out;

    // ws layout (halves): pad [4*PADTOT_AL*32] | w3 [294912]
    const size_t pad_halves = 4ull * PADTOT_AL * 32ull;     // 13,779,968
    const size_t need_bytes = (pad_halves + 294912ull) * 2ull;  // ~28.15 MB

    if (ws_size >= need_bytes) {
        unsigned short* pad = (unsigned short*)d_ws;
        unsigned short* w3  = pad + pad_halves;
        prep_kernel<<<1152 + 114, 256, 0, stream>>>(w, w3, pad);
        intrans_kernel<<<32 * HW, 256, 0, stream>>>(in, pad);
        conv_pipe2<<<(GEMM_N / 128) * (K_OUT / 128), 256, 0, stream>>>(pad, w3, bias, out);
    } else {
        dim3 grid(GEMM_N / 128, K_OUT / 128);
        conv_mfma_fallback<<<grid, 256, 0, stream>>>(in, w, bias, out);
    }
}

// Round 15
// 99.468 us; speedup vs baseline: 1.3533x; 1.1892x over previous
//
#include <hip/hip_runtime.h>
#include <hip/hip_bf16.h>
#include <stdint.h>

// DenseConv2d: input (32,128,56,56) f32, weight (256,128,3,3) f32, bias (256) f32
// stride 1, pad 1 -> out (32,256,56,56) f32.
// Round 15: r12's verified half-tile rotated-staging schedule at 128x128 tile:
// 4 waves (64x64 each), 2x32KB LDS double-buffer -> 2 BLOCKS/CU (cross-block
// anti-phase: one block's LDS bursts overlap the other's MFMA bursts) and
// grid 1568 (tail 1.07x vs r11's 1.31x). Counted vmcnt(4)/lgkmcnt(4), af1
// prefetch over MFMA0, chunked conflict-free LDS, fused prepass.

typedef __attribute__((ext_vector_type(8))) short bf16x8;
typedef __attribute__((ext_vector_type(8))) unsigned short ushort8;
typedef __attribute__((ext_vector_type(4))) float f32x4;

#define HW       56
#define SPATIAL  3136
#define C_IN     128
#define K_OUT    256
#define GEMM_K   1152
#define GEMM_N   100352      // 32*3136

#define PHW      58
#define PIMG     3364        // 58*58
#define PADTOT_AL 107656     // 32*3364 + 8 slack positions

#define NTILE    18          // K-tiles of 64 (tap = t>>1, ch-half = t&1)
#define BUFH     16384       // halves per LDS buffer: A 8192 + B 8192 (32 KiB)

__device__ __forceinline__ unsigned short f2bf(float f) {
    union { float f; unsigned int u; } v; v.f = f;
    unsigned int u = v.u + 0x7FFFu + ((v.u >> 16) & 1u);   // RTNE
    return (unsigned short)(u >> 16);
}

__device__ __forceinline__ void gload16(const unsigned short* g, unsigned short* l) {
    __builtin_amdgcn_global_load_lds(
        (const __attribute__((address_space(1))) unsigned int*)(g),
        (__attribute__((address_space(3))) unsigned int*)(l),
        16, 0, 0);
}

// fused prepass: blocks 0..1151 -> weight transform; 1152..1265 -> border zero.
// w3 chunk (rc,tap,cc) = 512 halves; slot s = l*8+j holds
// W[row rc*16 + (l&15)][ch cc*32 + (l>>4)*8 + j][tap]  (one wave A-fragment).
__global__ __launch_bounds__(256)
void prep_kernel(const float* __restrict__ w, unsigned short* __restrict__ w3,
                 unsigned short* __restrict__ pad) {
    if (blockIdx.x < 1152) {
        int idx = blockIdx.x * 256 + threadIdx.x;    // 294912
        int rc   = idx / 18432;
        int rem  = idx % 18432;
        int tap  = rem / 2048;
        int rem2 = rem % 2048;
        int cc   = rem2 / 512;
        int s    = rem2 % 512;
        int l    = s >> 3, j = s & 7;
        int ko   = rc * 16 + (l & 15);
        int c    = cc * 32 + ((l >> 4) << 3) + j;
        w3[idx] = f2bf(w[(ko * C_IN + c) * 9 + tap]);
    } else {
        int idx = (blockIdx.x - 1152) * 256 + threadIdx.x;   // 4*32*228 = 29184
        if (idx >= 29184) return;
        int cc  = idx / 7296;
        int r   = idx % 7296;
        int img = r / 228;
        int p   = r % 228;
        int pos;
        if (p < 58)       pos = p;
        else if (p < 116) pos = 57 * PHW + (p - 58);
        else { int i = p - 116; pos = (1 + (i >> 1)) * PHW + (i & 1) * 57; }
        unsigned short* d = pad + (size_t)cc * PADTOT_AL * 32
                          + ((size_t)img * PIMG + pos) * 32;
        const ushort8 z = (ushort8){0,0,0,0,0,0,0,0};
        *reinterpret_cast<ushort8*>(d)      = z;
        *reinterpret_cast<ushort8*>(d + 8)  = z;
        *reinterpret_cast<ushort8*>(d + 16) = z;
        *reinterpret_cast<ushort8*>(d + 24) = z;
    }
}

// input [32][128][56][56] f32 -> pad[4cc][32img][58*58][32ch] bf16 (interior)
__global__ __launch_bounds__(256)
void intrans_kernel(const float* __restrict__ in, unsigned short* __restrict__ pad) {
    __shared__ __attribute__((aligned(16))) unsigned short l[56 * 136];
    const int bx = blockIdx.x;                   // 32*56
    const int n = bx / HW, h = bx % HW;
    const int tid = threadIdx.x;
    const float* src = in + (size_t)n * C_IN * SPATIAL + h * HW;
    #pragma unroll
    for (int i = 0; i < 28; ++i) {               // 7168 = 28*256
        int idx = i * 256 + tid;
        int c = idx / HW, w = idx % HW;
        l[w * 136 + c] = f2bf(src[(size_t)c * SPATIAL + w]);
    }
    __syncthreads();
    const int prow = n * PIMG + (h + 1) * PHW;
    #pragma unroll
    for (int j = 0; j < 4; ++j) {
        int chunk = j * 256 + tid;               // 896 = 56*16 chunks of 8 halves
        if (chunk < 896) {
            int w = chunk >> 4, c8 = chunk & 15;
            int cc = c8 >> 2, sub = c8 & 3;
            unsigned short* dst = pad + (size_t)cc * PADTOT_AL * 32
                                + (size_t)(prow + w + 1) * 32 + sub * 8;
            *reinterpret_cast<ushort8*>(dst) =
                *reinterpret_cast<const ushort8*>(&l[w * 136 + c8 * 8]);
        }
    }
}

// ---------------- main kernel ----------------
// LDS buffer (halves): A chunks [(rc*2+kc)*512] rc=0..7; B at 8192:
// [(bc*2+kc)*512] bc=0..7. Chunk slot l = (row/col l&15, k-gran l>>4).
__global__ __launch_bounds__(256, 2)
void conv_kd(const unsigned short* __restrict__ pad,   // [4][PADTOT_AL][32]
             const unsigned short* __restrict__ w3,    // chunked weights
             const float* __restrict__ bias,
             float* __restrict__ out) {
    __shared__ __attribute__((aligned(16))) unsigned short lds[2 * BUFH]; // 64 KiB

    const int tid  = threadIdx.x;
    const int wave = tid >> 6;          // 0..3
    const int lane = tid & 63;
    const int la   = lane & 15;
    const int lkh  = lane >> 4;

    // bijective XCD swizzle: 1568 blocks = 8 * 196; m-pairs adjacent for L2 B reuse
    const int bid = blockIdx.x;
    const int swz = (bid & 7) * 196 + (bid >> 3);
    const int mt  = swz & 1, nt = swz >> 1;       // nt 0..783
    const int m0  = mt * 128;
    const int g0  = nt * 128;

    const int wr = wave >> 1, wc = wave & 1;      // 2x2 waves, 64x64 tiles

    // ---- staging descriptors (wave covers rc/bc = 2*wave, 2*wave+1) ----
    const unsigned short* aw0 = w3 + (size_t)(mt * 8 + wave * 2 + 0) * 18432 + lane * 8;
    const unsigned short* aw1 = w3 + (size_t)(mt * 8 + wave * 2 + 1) * 18432 + lane * 8;
    const unsigned short* bsrc0;
    const unsigned short* bsrc1;
    {
        int col = g0 + (wave * 2 + 0) * 16 + la;
        int img = col / SPATIAL;
        int pos = col - img * SPATIAL;
        int oh  = pos / HW, ow = pos - oh * HW;
        bsrc0 = pad + (size_t)(img * PIMG + (oh + 1) * PHW + (ow + 1)) * 32 + lkh * 8;
        col = g0 + (wave * 2 + 1) * 16 + la;
        img = col / SPATIAL;
        pos = col - img * SPATIAL;
        oh  = pos / HW; ow = pos - oh * HW;
        bsrc1 = pad + (size_t)(img * PIMG + (oh + 1) * PHW + (ow + 1)) * 32 + lkh * 8;
    }

    f32x4 acc[4][4];
    #pragma unroll
    for (int i = 0; i < 4; ++i)
        #pragma unroll
        for (int j = 0; j < 4; ++j)
            acc[i][j] = (f32x4){0.f, 0.f, 0.f, 0.f};

    // stage half kc of tile tn into buf[tn&1]: 4 gloads per wave
    auto STAGE = [&](int tn, int kc) {
        const int tap = tn >> 1;
        const int cc  = (tn & 1) * 2 + kc;            // global 32-ch chunk 0..3
        const int dr = tap / 3 - 1, dsx = tap % 3 - 1;
        unsigned short* dst = &lds[(tn & 1) * BUFH];
        const ptrdiff_t bofs = (ptrdiff_t)cc * (PADTOT_AL * 32) + (dr * PHW + dsx) * 32;
        gload16(aw0 + (size_t)(tap * 4 + cc) * 512, dst + ((wave * 2 + 0) * 2 + kc) * 512);
        gload16(aw1 + (size_t)(tap * 4 + cc) * 512, dst + ((wave * 2 + 1) * 2 + kc) * 512);
        gload16(bsrc0 + bofs, dst + 8192 + ((wave * 2 + 0) * 2 + kc) * 512);
        gload16(bsrc1 + bofs, dst + 8192 + ((wave * 2 + 1) * 2 + kc) * 512);
    };

    bf16x8 af0[4], af1[4], bv0[4], bv1[4];

    // prologue: tile0 both halves + tile1 h0 (12 loads/wave); wait tile0 -> vmcnt(4)
    STAGE(0, 0); STAGE(0, 1); STAGE(1, 0);
    asm volatile("s_waitcnt vmcnt(4)" ::: "memory");
    __builtin_amdgcn_s_barrier();

    #pragma unroll
    for (int t = 0; t < NTILE; ++t) {
        const unsigned short* Ab = &lds[(t & 1) * BUFH];

        // ---- phase ks0 ----
        #pragma unroll
        for (int mi = 0; mi < 4; ++mi)
            af0[mi] = *reinterpret_cast<const bf16x8*>(
                &Ab[((wr * 4 + mi) * 2 + 0) * 512 + lane * 8]);
        #pragma unroll
        for (int nj = 0; nj < 4; ++nj)
            bv0[nj] = *reinterpret_cast<const bf16x8*>(
                &Ab[8192 + ((wc * 4 + nj) * 2 + 0) * 512 + lane * 8]);
        // prefetch ks1 A-frags: fly over MFMA0
        #pragma unroll
        for (int mi = 0; mi < 4; ++mi)
            af1[mi] = *reinterpret_cast<const bf16x8*>(
                &Ab[((wr * 4 + mi) * 2 + 1) * 512 + lane * 8]);

        asm volatile("s_waitcnt lgkmcnt(4)" ::: "memory");  // af0+bv0 done, af1 flying
        __builtin_amdgcn_sched_barrier(0);
        __builtin_amdgcn_s_setprio(1);
        #pragma unroll
        for (int mi = 0; mi < 4; ++mi)
            #pragma unroll
            for (int nj = 0; nj < 4; ++nj)
                acc[mi][nj] = __builtin_amdgcn_mfma_f32_16x16x32_bf16(
                    af0[mi], bv0[nj], acc[mi][nj], 0, 0, 0);
        __builtin_amdgcn_s_setprio(0);

        __builtin_amdgcn_s_barrier();   // all waves' h0 reads drained (lgkm<=4 = af1, h1)

        // ---- phase ks1 ----
        #pragma unroll
        for (int nj = 0; nj < 4; ++nj)
            bv1[nj] = *reinterpret_cast<const bf16x8*>(
                &Ab[8192 + ((wc * 4 + nj) * 2 + 1) * 512 + lane * 8]);
        if (t + 1 < NTILE) STAGE(t + 1, 1);   // other buffer h1
        if (t + 2 < NTILE) STAGE(t + 2, 0);   // this buffer h0: safe after mid barrier

        asm volatile("s_waitcnt lgkmcnt(0)" ::: "memory");  // af1+bv1 done
        __builtin_amdgcn_sched_barrier(0);
        __builtin_amdgcn_s_setprio(1);
        #pragma unroll
        for (int mi = 0; mi < 4; ++mi)
            #pragma unroll
            for (int nj = 0; nj < 4; ++nj)
                acc[mi][nj] = __builtin_amdgcn_mfma_f32_16x16x32_bf16(
                    af1[mi], bv1[nj], acc[mi][nj], 0, 0, 0);
        __builtin_amdgcn_s_setprio(0);

        // end of tile: tile t+1's 8 loads landed; t+2 h0's 4 stay in flight
        if (t < NTILE - 2) {
            asm volatile("s_waitcnt vmcnt(4)" ::: "memory");
            __builtin_amdgcn_s_barrier();
        } else if (t == NTILE - 2) {
            asm volatile("s_waitcnt vmcnt(0)" ::: "memory");
            __builtin_amdgcn_s_barrier();
        }
    }

    // ---- epilogue: D col = lane&15, row = (lane>>4)*4 + reg ----
    #pragma unroll
    for (int mi = 0; mi < 4; ++mi) {
        const int mb = m0 + wr * 64 + mi * 16 + lkh * 4;
        const f32x4 bv4 = *reinterpret_cast<const f32x4*>(&bias[mb]);
        #pragma unroll
        for (int nj = 0; nj < 4; ++nj) {
            const int gcol = g0 + wc * 64 + nj * 16;   // 16-aligned: one image
            const int n2 = gcol / SPATIAL;
            const int p2 = gcol - n2 * SPATIAL + la;
            float* op = out + ((size_t)(n2 * K_OUT + mb)) * SPATIAL + p2;
            op[0]                   = acc[mi][nj][0] + bv4[0];
            op[SPATIAL]             = acc[mi][nj][1] + bv4[1];
            op[2 * SPATIAL]         = acc[mi][nj][2] + bv4[2];
            op[3 * (size_t)SPATIAL] = acc[mi][nj][3] + bv4[3];
        }
    }
}

// ---------------- fallback (round-1 path) if ws is too small ----------------
#define LDK 40
__global__ __launch_bounds__(256)
void conv_mfma_fallback(const float* __restrict__ in,
                        const float* __restrict__ wraw,
                        const float* __restrict__ bias,
                        float* __restrict__ out) {
    __shared__ __attribute__((aligned(16))) unsigned short lA[128 * LDK];
    __shared__ __attribute__((aligned(16))) unsigned short lB[128 * LDK];
    const int tid = threadIdx.x;
    const int m0  = blockIdx.y * 128;
    const int g0  = blockIdx.x * 128;
    const int wave = tid >> 6, lane = tid & 63;
    const int wr = wave >> 1, wc = wave & 1;
    const int la = lane & 15, lkh = lane >> 4, lk = lkh * 8;

    f32x4 acc[4][4];
    #pragma unroll
    for (int i = 0; i < 4; ++i)
        #pragma unroll
        for (int j = 0; j < 4; ++j)
            acc[i][j] = (f32x4){0.f, 0.f, 0.f, 0.f};

    const int jj = tid & 127;
    const int kb = (tid >> 7) * 16;
    const int g = g0 + jj;
    const int nimg = g / SPATIAL;
    const int pos  = g % SPATIAL;
    const int oh = pos / HW, ow = pos % HW;

    for (int tap = 0; tap < 9; ++tap) {
        const int dr = tap / 3 - 1, dsx = tap % 3 - 1;
        const int ih = oh + dr, iw = ow + dsx;
        const bool valid = ((unsigned)ih < HW) && ((unsigned)iw < HW);
        const float* src = in + ((nimg * C_IN) * HW + ih) * HW + iw;
        for (int c0 = 0; c0 < C_IN; c0 += 32) {
            #pragma unroll
            for (int i = 0; i < 2; ++i) {
                const int ch = tid * 2 + i;
                const int row = ch >> 2;
                const int kp = (ch & 3) * 8;
                ushort8 v;
                #pragma unroll
                for (int e = 0; e < 8; ++e)
                    v[e] = f2bf(wraw[((m0 + row) * C_IN + c0 + kp + e) * 9 + tap]);
                *reinterpret_cast<ushort8*>(&lA[row * LDK + kp]) = v;
            }
            {
                ushort8 v0, v1;
                #pragma unroll
                for (int i = 0; i < 8; ++i)
                    v0[i] = f2bf(valid ? src[(c0 + kb + i) * SPATIAL] : 0.f);
                #pragma unroll
                for (int i = 0; i < 8; ++i)
                    v1[i] = f2bf(valid ? src[(c0 + kb + 8 + i) * SPATIAL] : 0.f);
                *reinterpret_cast<ushort8*>(&lB[jj * LDK + kb])     = v0;
                *reinterpret_cast<ushort8*>(&lB[jj * LDK + kb + 8]) = v1;
            }
            __syncthreads();
            bf16x8 af[4], bv[4];
            #pragma unroll
            for (int f = 0; f < 4; ++f) {
                af[f] = *reinterpret_cast<const bf16x8*>(&lA[(wr * 64 + f * 16 + la) * LDK + lk]);
                bv[f] = *reinterpret_cast<const bf16x8*>(&lB[(wc * 64 + f * 16 + la) * LDK + lk]);
            }
            #pragma unroll
            for (int fi = 0; fi < 4; ++fi)
                #pragma unroll
                for (int fj = 0; fj < 4; ++fj)
                    acc[fi][fj] = __builtin_amdgcn_mfma_f32_16x16x32_bf16(
                        af[fi], bv[fj], acc[fi][fj], 0, 0, 0);
            __syncthreads();
        }
    }
    const int mbase = m0 + wr * 64;
    const int cbase = g0 + wc * 64;
    #pragma unroll
    for (int fi = 0; fi < 4; ++fi) {
        float bvv[4];
        #pragma unroll
        for (int r = 0; r < 4; ++r)
            bvv[r] = bias[mbase + fi * 16 + lkh * 4 + r];
        #pragma unroll
        for (int fj = 0; fj < 4; ++fj) {
            const int gcol = cbase + fj * 16 + la;
            const int n2 = gcol / SPATIAL;
            const int p2 = gcol % SPATIAL;
            float* op = out + (size_t)(n2 * K_OUT) * SPATIAL + p2;
            #pragma unroll
            for (int r = 0; r < 4; ++r)
                op[(size_t)(mbase + fi * 16 + lkh * 4 + r) * SPATIAL] = acc[fi][fj][r] + bvv[r];
        }
    }
}

extern "C" void kernel_launch(void* const* d_in, const int* in_sizes, int n_in,
                              void* d_out, int out_size, void* d_ws, size_t ws_size,
                              hipStream_t stream) {
    const float* in   = (const float*)d_in[0];
    const float* w    = (const float*)d_in[1];
    const float* bias = (const float*)d_in[2];
    float* out = (float*)d_out;

    // ws layout (halves): pad [4*PADTOT_AL*32] | w3 [294912]
    const size_t pad_halves = 4ull * PADTOT_AL * 32ull;     // 13,779,968
    const size_t need_bytes = (pad_halves + 294912ull) * 2ull;  // ~28.15 MB

    if (ws_size >= need_bytes) {
        unsigned short* pad = (unsigned short*)d_ws;
        unsigned short* w3  = pad + pad_halves;
        prep_kernel<<<1152 + 114, 256, 0, stream>>>(w, w3, pad);
        intrans_kernel<<<32 * HW, 256, 0, stream>>>(in, pad);
        conv_kd<<<(GEMM_N / 128) * (K_OUT / 128), 256, 0, stream>>>(pad, w3, bias, out);
    } else {
        dim3 grid(GEMM_N / 128, K_OUT / 128);
        conv_mfma_fallback<<<grid, 256, 0, stream>>>(in, w, bias, out);
    }
}